// Round 19
// baseline (82.042 us; speedup 1.0000x reference)
//
#include <hip/hip_runtime.h>
#include <math.h>

#define N0 200000
#define N1 1024
#define N2 256
#define N3 32
#define NE0 2048000
#define NE1 262144
#define NE2 8192
#define BATCH 32
#define NCLS 10
#define NB 4             // src-range buckets for gather0 (XCD L2 partitioning)
#define SRC_PER_B 50000  // N0 / NB
#define TBLOCKS 3125     // transpose tiles (64 cols each)
#define PREBLOCKS (N1 + TBLOCKS)  // 1024 partition FIRST, then transpose

typedef _Float16 h2 __attribute__((ext_vector_type(2)));
typedef _Float16 h8 __attribute__((ext_vector_type(8)));

__device__ __forceinline__ int lower_bound_i(const int* __restrict__ a, int n, int key) {
    int lo = 0, hi = n;
    while (lo < hi) {
        int mid = (lo + hi) >> 1;
        if (a[mid] < key) lo = mid + 1; else hi = mid;
    }
    return lo;
}

// Fused pre-pass (round-16 exact). Blocks [0, N1): partition role for
// dst0-segment i -- FIRST in dispatch order, i%8 covers all XCD residues.
// Blocks [N1, N1+TBLOCKS): transpose tile i-N1.
__global__ __launch_bounds__(256) void k_pre(const float* __restrict__ x,
                                             h2* __restrict__ xt,
                                             const int* __restrict__ src,
                                             const int* __restrict__ dst,
                                             int* __restrict__ esrc,
                                             int* __restrict__ bstart) {
    const int i = blockIdx.x;
    const int tid = threadIdx.x;
    if (i >= N1) {
        // ---- transpose role ----
        const int t = i - N1;
        __shared__ float tile[32][65];
        const int col0 = t * 64;
        const int c = tid & 63, r0 = tid >> 6;       // 4 row-lanes
        #pragma unroll
        for (int r = r0; r < 32; r += 4) {
            int col = col0 + c;
            tile[r][c] = (col < N0) ? x[r * N0 + col] : 0.f;
        }
        __syncthreads();
        const int bb = (tid & 15) * 2, c0 = tid >> 4; // 16 col-lanes, 2 batches
        #pragma unroll
        for (int cc = c0; cc < 64; cc += 16) {
            int col = col0 + cc;
            if (col < N0) {
                h2 v;
                v[0] = (_Float16)tile[bb][cc];
                v[1] = (_Float16)tile[bb + 1][cc];
                xt[col * 16 + (bb >> 1)] = v;
            }
        }
        return;
    }
    // ---- partition role (one block per dst0 segment) ----
    const int n = i;
    const int e0 = lower_bound_i(dst, NE0, n);
    const int e1 = lower_bound_i(dst, NE0, n + 1);
    const int len = e1 - e0;
    const int wave = tid >> 6, lane = tid & 63;
    const int q0 = e0 + (len * wave) / 4;
    const int q1 = e0 + (len * (wave + 1)) / 4;
    __shared__ int wcnt[4][NB];
    __shared__ int wbase[4][NB];

    // phase 1: per-wave bucket counts via ballot (no atomics)
    int c0 = 0, c1 = 0, c2 = 0, c3 = 0;
    for (int base = q0; base < q1; base += 64) {
        int e = base + lane;
        int b = -1;
        if (e < q1) b = src[e] / SRC_PER_B;
        c0 += __popcll(__ballot(b == 0));
        c1 += __popcll(__ballot(b == 1));
        c2 += __popcll(__ballot(b == 2));
        c3 += __popcll(__ballot(b == 3));
    }
    if (lane == 0) { wcnt[wave][0] = c0; wcnt[wave][1] = c1; wcnt[wave][2] = c2; wcnt[wave][3] = c3; }
    __syncthreads();
    if (tid == 0) {
        int acc = e0;
        #pragma unroll
        for (int b = 0; b < NB; ++b) {
            bstart[n * (NB + 1) + b] = acc;
            #pragma unroll
            for (int w = 0; w < 4; ++w) { wbase[w][b] = acc; acc += wcnt[w][b]; }
        }
        bstart[n * (NB + 1) + NB] = acc;   // == e1
    }
    __syncthreads();

    // phase 2: stable scatter (deterministic order), register cursors
    int u0 = wbase[wave][0], u1 = wbase[wave][1], u2 = wbase[wave][2], u3 = wbase[wave][3];
    for (int base = q0; base < q1; base += 64) {
        int e = base + lane;
        int s = 0, b = -1;
        if (e < q1) { s = src[e]; b = s / SRC_PER_B; }
        unsigned long long m0 = __ballot(b == 0);
        unsigned long long m1 = __ballot(b == 1);
        unsigned long long m2 = __ballot(b == 2);
        unsigned long long m3 = __ballot(b == 3);
        unsigned long long lt = (1ull << lane) - 1ull;
        if (b == 0)      esrc[u0 + __popcll(m0 & lt)] = s;
        else if (b == 1) esrc[u1 + __popcll(m1 & lt)] = s;
        else if (b == 2) esrc[u2 + __popcll(m2 & lt)] = s;
        else if (b == 3) esrc[u3 + __popcll(m3 & lt)] = s;
        u0 += __popcll(m0); u1 += __popcll(m1); u2 += __popcll(m2); u3 += __popcll(m3);
    }
}

// Layer-0 gather over bucket-partitioned edges (round-16 exact).
// NOTE: idempotent (pure function of xt/esrc/bstart -> p0p) -- this round
// launches it TWICE as an attribution probe; Δtotal = its warm duration.
__global__ __launch_bounds__(128) void k_gather0s(const h8* __restrict__ table,
                                                  const int* __restrict__ esrc,
                                                  const int* __restrict__ bstart,
                                                  _Float16* __restrict__ p0p) {
    const int b = blockIdx.x & (NB - 1);
    const int n = blockIdx.x >> 2;
    const int q0 = bstart[n * (NB + 1) + b];
    const int q1 = bstart[n * (NB + 1) + b + 1];
    const int tid = threadIdx.x;
    const int b4 = tid & 3;      // which 16B chunk of the 64B row
    const int g  = tid >> 2;     // 32 edge groups
    float acc[8] = {0.f, 0.f, 0.f, 0.f, 0.f, 0.f, 0.f, 0.f};
    int e = q0 + g;
    for (; e + 96 < q1; e += 128) {
        int s0 = esrc[e];
        int s1 = esrc[e + 32];
        int s2 = esrc[e + 64];
        int s3 = esrc[e + 96];
        h8 v0 = table[s0 * 4 + b4];
        h8 v1 = table[s1 * 4 + b4];
        h8 v2 = table[s2 * 4 + b4];
        h8 v3 = table[s3 * 4 + b4];
        #pragma unroll
        for (int i = 0; i < 8; ++i)
            acc[i] += (float)v0[i] + (float)v1[i] + (float)v2[i] + (float)v3[i];
    }
    for (; e < q1; e += 32) {
        int s = esrc[e];
        h8 v = table[s * 4 + b4];
        #pragma unroll
        for (int i = 0; i < 8; ++i) acc[i] += (float)v[i];
    }
    __shared__ float red[32][33];
    #pragma unroll
    for (int i = 0; i < 8; ++i) red[g][b4 * 8 + i] = acc[i];
    __syncthreads();
    #pragma unroll
    for (int s = 16; s >= 1; s >>= 1) {
        if (g < s) {
            #pragma unroll
            for (int i = 0; i < 8; ++i)
                red[g][b4 * 8 + i] += red[g + s][b4 * 8 + i];
        }
        __syncthreads();
    }
    if (tid < 32) p0p[(b * N1 + n) * 32 + tid] = (_Float16)red[0][tid];
}

// Dispatch 3: blocks [0,N2) = layer-1 gather (sums the NB fp16 partial
// planes inline); blocks [N2, N2+NCLS) = weight-chain + Vfc precompute.
__global__ __launch_bounds__(256) void k_gather1w(
    const h8* __restrict__ p0p, const int* __restrict__ src,
    const int* __restrict__ dst, _Float16* __restrict__ out_h,
    float* __restrict__ cnt_out,
    const float* __restrict__ V0, const float* __restrict__ g0, const float* __restrict__ b0,
    const float* __restrict__ V1, const float* __restrict__ g1, const float* __restrict__ b1,
    const float* __restrict__ V2, const float* __restrict__ g2, const float* __restrict__ b2,
    const float* __restrict__ Vfc, const float* __restrict__ gfc,
    float* __restrict__ M_, float* __restrict__ Q2_, float* __restrict__ R2_,
    float* __restrict__ B4_) {
    const int tid = threadIdx.x;
    if (blockIdx.x < N2) {
        // ---- gather1 role ----
        const int n = blockIdx.x;
        const int e0 = lower_bound_i(dst, NE1, n);
        const int e1 = lower_bound_i(dst, NE1, n + 1);
        const int b4 = tid & 3;
        const int g  = tid >> 2;
        float acc[8] = {0.f, 0.f, 0.f, 0.f, 0.f, 0.f, 0.f, 0.f};
        for (int e = e0 + g; e < e1; e += 64) {
            int s = src[e];
            h8 v0 = p0p[0 * N1 * 4 + s * 4 + b4];
            h8 v1 = p0p[1 * N1 * 4 + s * 4 + b4];
            h8 v2 = p0p[2 * N1 * 4 + s * 4 + b4];
            h8 v3 = p0p[3 * N1 * 4 + s * 4 + b4];
            #pragma unroll
            for (int i = 0; i < 8; ++i)
                acc[i] += ((float)v0[i] + (float)v1[i]) + ((float)v2[i] + (float)v3[i]);
        }
        __shared__ float red[64][33];
        #pragma unroll
        for (int i = 0; i < 8; ++i) red[g][b4 * 8 + i] = acc[i];
        __syncthreads();
        #pragma unroll
        for (int s = 32; s >= 1; s >>= 1) {
            if (g < s) {
                #pragma unroll
                for (int i = 0; i < 8; ++i)
                    red[g][b4 * 8 + i] += red[g + s][b4 * 8 + i];
            }
            __syncthreads();
        }
        if (tid < 32) out_h[n * 32 + tid] = (_Float16)red[0][tid];
        else if (tid == 32) cnt_out[n] = (float)(e1 - e0);
        return;
    }
    // ---- weights role: class k ----
    const int k = blockIdx.x - N2;
    __shared__ float w0[32], u[64], v[64], p[128], q[128], r[128];
    __shared__ float redA[8][32], redB[8][32], redC[8][32], redD[8][32];
    __shared__ float nnred[4];
    __shared__ float scale_s;

    if (tid < 32) {
        float val = V0[tid];
        w0[tid] = g0[tid] * val / fabsf(val);
    }
    __syncthreads();
    if (tid < 64) {
        float nn = 0.f;
        #pragma unroll
        for (int c = 0; c < 32; ++c) { float t = V1[tid * 32 + c]; nn += t * t; }
        float inv = g1[tid] * rsqrtf(nn);
        float su = 0.f, sv = 0.f;
        #pragma unroll
        for (int c = 0; c < 32; ++c) {
            float w = V1[tid * 32 + c] * inv;
            su += w * w0[c]; sv += w * b0[c];
        }
        u[tid] = su; v[tid] = sv;
    }
    __syncthreads();
    if (tid < 128) {
        float nn = 0.f;
        #pragma unroll
        for (int c = 0; c < 64; ++c) { float t = V2[tid * 64 + c]; nn += t * t; }
        float inv = g2[tid] * rsqrtf(nn);
        float sp = 0.f, sq = 0.f, sr = 0.f;
        #pragma unroll
        for (int c = 0; c < 64; ++c) {
            float w = V2[tid * 64 + c] * inv;
            sp += w * u[c]; sq += w * v[c]; sr += w * b1[c];
        }
        p[tid] = sp; q[tid] = sq; r[tid] = sr;
    }
    __syncthreads();

    const int n3 = tid & 31, og = tid >> 5;
    float nn = 0.f, mk = 0.f, mq = 0.f, mr = 0.f, mb = 0.f;
    #pragma unroll
    for (int i = 0; i < 16; ++i) {
        int o = og + 8 * i;
        float w = Vfc[k * 4096 + tid + 256 * i];
        nn += w * w;
        mk += w * p[o]; mq += w * q[o]; mr += w * r[o]; mb += w * b2[o];
    }
    #pragma unroll
    for (int off = 32; off; off >>= 1) nn += __shfl_xor(nn, off);
    if ((tid & 63) == 0) nnred[tid >> 6] = nn;
    redA[og][n3] = mk; redB[og][n3] = mq; redC[og][n3] = mr; redD[og][n3] = mb;
    __syncthreads();
    if (tid == 0) {
        float s = nnred[0] + nnred[1] + nnred[2] + nnred[3];
        scale_s = gfc[k] * rsqrtf(s);
    }
    __syncthreads();
    if (tid < 32) {
        float smk = 0.f, smq = 0.f, smr = 0.f, smb = 0.f;
        #pragma unroll
        for (int i = 0; i < 8; ++i) {
            smk += redA[i][tid]; smq += redB[i][tid];
            smr += redC[i][tid]; smb += redD[i][tid];
        }
        float scale = scale_s;
        M_[k * 32 + tid]  = scale * smk;
        Q2_[k * 32 + tid] = scale * smq;
        R2_[k * 32 + tid] = scale * smr;
        float bs = scale * smb;
        #pragma unroll
        for (int off = 16; off; off >>= 1) bs += __shfl_xor(bs, off);
        if (tid == 0) B4_[k] = bs;
    }
}

// Layer-2 gather (32 segments, 16 KB table): writes fp32 S2, T2, cnt2.
__global__ __launch_bounds__(256) void k_gather2(const h8* __restrict__ table,
                                                 const int* __restrict__ src,
                                                 const int* __restrict__ dst,
                                                 const float* __restrict__ cnt_in,
                                                 float* __restrict__ out_f,
                                                 float* __restrict__ cnt_out,
                                                 float* __restrict__ t_out) {
    const int n = blockIdx.x;
    const int e0 = lower_bound_i(dst, NE2, n);
    const int e1 = lower_bound_i(dst, NE2, n + 1);
    const int tid = threadIdx.x;
    const int b4 = tid & 3;
    const int g  = tid >> 2;
    float acc[8] = {0.f, 0.f, 0.f, 0.f, 0.f, 0.f, 0.f, 0.f};
    float tacc = 0.f;
    for (int e = e0 + g; e < e1; e += 64) {
        int s = src[e];
        h8 v = table[s * 4 + b4];
        #pragma unroll
        for (int i = 0; i < 8; ++i) acc[i] += (float)v[i];
        if (b4 == 0) tacc += cnt_in[s];
    }
    __shared__ float red[64][33];
    __shared__ float tred[64];
    #pragma unroll
    for (int i = 0; i < 8; ++i) red[g][b4 * 8 + i] = acc[i];
    if (b4 == 0) tred[g] = tacc;
    __syncthreads();
    #pragma unroll
    for (int s = 32; s >= 1; s >>= 1) {
        if (g < s) {
            #pragma unroll
            for (int i = 0; i < 8; ++i)
                red[g][b4 * 8 + i] += red[g + s][b4 * 8 + i];
            if (b4 == 0) tred[g] += tred[g + s];
        }
        __syncthreads();
    }
    if (tid < 32) out_f[n * 32 + tid] = red[0][tid];
    else if (tid == 32) cnt_out[n] = (float)(e1 - e0);
    else if (tid == 33) t_out[n] = tred[0];
}

// Tiny final combine: block per class.
__global__ __launch_bounds__(64) void k_final(const float* __restrict__ M_,
                                              const float* __restrict__ Q2_,
                                              const float* __restrict__ R2_,
                                              const float* __restrict__ B4_,
                                              const float* __restrict__ bfc,
                                              const float* __restrict__ S2,
                                              const float* __restrict__ T2,
                                              const float* __restrict__ cnt2,
                                              float* __restrict__ out) {
    const int k = blockIdx.x;
    const int tid = threadIdx.x;
    __shared__ float Kc_s;
    float kc = 0.f;
    if (tid < 32)
        kc = Q2_[k * 32 + tid] * T2[tid] + R2_[k * 32 + tid] * cnt2[tid];
    #pragma unroll
    for (int off = 16; off; off >>= 1) kc += __shfl_xor(kc, off);
    if (tid == 0) Kc_s = kc + B4_[k] + bfc[k];
    __syncthreads();
    if (tid < 32) {
        int b = tid;
        float s = 0.f;
        #pragma unroll
        for (int n = 0; n < 32; ++n) s += M_[k * 32 + n] * S2[n * 32 + b];
        out[b * NCLS + k] = s + Kc_s;
    }
}

extern "C" void kernel_launch(void* const* d_in, const int* in_sizes, int n_in,
                              void* d_out, int out_size, void* d_ws, size_t ws_size,
                              hipStream_t stream) {
    const float* x   = (const float*)d_in[0];
    const int* src0  = (const int*)d_in[1];
    const int* dst0  = (const int*)d_in[2];
    const int* src1  = (const int*)d_in[3];
    const int* dst1  = (const int*)d_in[4];
    const int* src2  = (const int*)d_in[5];
    const int* dst2  = (const int*)d_in[6];
    const float* V0  = (const float*)d_in[7];
    const float* g0  = (const float*)d_in[8];
    const float* b0  = (const float*)d_in[9];
    const float* V1  = (const float*)d_in[10];
    const float* g1  = (const float*)d_in[11];
    const float* b1  = (const float*)d_in[12];
    const float* V2  = (const float*)d_in[13];
    const float* g2  = (const float*)d_in[14];
    const float* b2  = (const float*)d_in[15];
    const float* Vfc = (const float*)d_in[16];
    const float* gfc = (const float*)d_in[17];
    const float* bfc = (const float*)d_in[18];

    char* ws = (char*)d_ws;
    _Float16* xt   = (_Float16*)(ws);                // 12,800,000 B
    int* esrc      = (int*)(ws + 12800000);          // 8,192,000 B
    int* bstart    = (int*)(ws + 20992000);          // 20,480 B
    _Float16* P0p  = (_Float16*)(ws + 21012480);     // 262,144 B
    _Float16* S1h  = (_Float16*)(ws + 21274624);     // 16,384 B
    float* cnt1    = (float*)(ws + 21291008);        // 1,024 B
    float* S2      = (float*)(ws + 21292032);        // 4,096 B
    float* T2      = (float*)(ws + 21296128);        // 128 B
    float* cnt2    = (float*)(ws + 21296256);        // 128 B
    float* M_      = (float*)(ws + 21296384);        // 1,280 B
    float* Q2_     = (float*)(ws + 21297664);        // 1,280 B
    float* R2_     = (float*)(ws + 21298944);        // 1,280 B
    float* B4_     = (float*)(ws + 21300224);        // 40 B

    k_pre<<<PREBLOCKS, 256, 0, stream>>>(x, (h2*)xt, src0, dst0, esrc, bstart);
    k_gather0s<<<N1 * NB, 128, 0, stream>>>((const h8*)xt, esrc, bstart,
                                            (_Float16*)P0p);
    // ATTRIBUTION PROBE: duplicate launch (idempotent). Δtotal vs round-16's
    // 69.1 us = warm-L2 duration of k_gather0s + ~2 us launch overhead.
    k_gather0s<<<N1 * NB, 128, 0, stream>>>((const h8*)xt, esrc, bstart,
                                            (_Float16*)P0p);
    k_gather1w<<<N2 + NCLS, 256, 0, stream>>>((const h8*)P0p, src1, dst1,
                                              S1h, cnt1,
                                              V0, g0, b0, V1, g1, b1,
                                              V2, g2, b2, Vfc, gfc,
                                              M_, Q2_, R2_, B4_);
    k_gather2<<<N3, 256, 0, stream>>>((const h8*)S1h, src2, dst2, cnt1,
                                      S2, cnt2, T2);
    k_final<<<NCLS, 64, 0, stream>>>(M_, Q2_, R2_, B4_, bfc, S2, T2, cnt2,
                                     (float*)d_out);
}

// Round 20
// 65.208 us; speedup vs baseline: 1.2582x; 1.2582x over previous
//
#include <hip/hip_runtime.h>
#include <math.h>

#define N0 200000
#define N1 1024
#define N2 256
#define N3 32
#define NE0 2048000
#define NE1 262144
#define NE2 8192
#define BATCH 32
#define NCLS 10
#define NB 4             // src-range buckets for gather0 (XCD L2 partitioning)
#define SRC_PER_B 50000  // N0 / NB
#define TBLOCKS 1563     // transpose tiles (128 cols each, float4/h8 vectorized)
#define PREBLOCKS (N1 + TBLOCKS)  // 1024 partition FIRST, then transpose

typedef _Float16 h2 __attribute__((ext_vector_type(2)));
typedef _Float16 h8 __attribute__((ext_vector_type(8)));

__device__ __forceinline__ int lower_bound_i(const int* __restrict__ a, int n, int key) {
    int lo = 0, hi = n;
    while (lo < hi) {
        int mid = (lo + hi) >> 1;
        if (a[mid] < key) lo = mid + 1; else hi = mid;
    }
    return lo;
}

// Wave-parallel 64-ary lower_bound: each round, 64 lanes probe lo + i*step,
// ballot finds the last probe with dst[p] < key -> range narrows 64x.
// ~4 dependent rounds for 2M elements vs ~21 for serial binary search.
// Invariant: lb in [lo, hi]. Correct for any sorted array (no window assumption).
__device__ __forceinline__ int wave_lower_bound(const int* __restrict__ a,
                                                int n, int key, int lane) {
    int lo = 0, hi = n;
    while (lo < hi) {
        int range = hi - lo;
        int step = (range + 63) >> 6;       // ceil(range/64)
        int p = lo + lane * step;
        bool ok = (p < hi) && (a[p] < key);
        unsigned long long m = __ballot(ok);
        if (m == 0ull) break;                // a[lo] >= key -> lb == lo
        int L = 63 - __builtin_clzll(m);     // last lane with a[p] < key
        int nlo = lo + L * step + 1;         // lb > p_L
        int nhi = lo + (L + 1) * step;       // a[p_{L+1}] >= key (or past hi)
        hi = (nhi < hi) ? nhi : hi;
        lo = nlo;
    }
    return lo;
}

// Fused pre-pass. Blocks [0, N1): partition role for dst0-segment i (FIRST
// in dispatch order; i%8 covers all XCD residues -- round-15/16 lessons).
// Blocks [N1, N1+TBLOCKS): float4-read / h8-write vectorized transpose.
// Partition bounds via wave-parallel 64-ary search (waves 0/1 find e0/e1
// concurrently) -- kills the ~40-deep serial probe chain (round-19 probe
// showed k_pre ~35-40 us was the pipeline's pole).
__global__ __launch_bounds__(256) void k_pre(const float* __restrict__ x,
                                             h2* __restrict__ xt,
                                             const int* __restrict__ src,
                                             const int* __restrict__ dst,
                                             int* __restrict__ esrc,
                                             int* __restrict__ bstart) {
    const int i = blockIdx.x;
    const int tid = threadIdx.x;
    if (i >= N1) {
        // ---- transpose role: 128 cols x 32 rows, float4 in, h8 out ----
        const int t = i - N1;
        __shared__ float tile[32][129];
        const int col0 = t * 128;
        #pragma unroll
        for (int pass = 0; pass < 4; ++pass) {
            int row = (tid >> 5) + 8 * pass;
            int j4 = (tid & 31) * 4;
            int col = col0 + j4;
            if (col < N0) {   // N0 % 4 == 0 -> whole float4 in-bounds
                const float4 v = *reinterpret_cast<const float4*>(&x[row * N0 + col]);
                tile[row][j4]     = v.x;
                tile[row][j4 + 1] = v.y;
                tile[row][j4 + 2] = v.z;
                tile[row][j4 + 3] = v.w;
            }
        }
        __syncthreads();
        h8* xt8 = reinterpret_cast<h8*>(xt);
        #pragma unroll
        for (int k = 0; k < 2; ++k) {
            int cl = (tid >> 2) + 64 * k;
            int col = col0 + cl;
            int c4 = tid & 3;
            if (col < N0) {
                h8 v;
                #pragma unroll
                for (int ii = 0; ii < 8; ++ii)
                    v[ii] = (_Float16)tile[8 * c4 + ii][cl];
                xt8[col * 4 + c4] = v;   // consecutive tid -> consecutive 16 B
            }
        }
        return;
    }
    // ---- partition role (one block per dst0 segment) ----
    const int n = i;
    const int wave = tid >> 6, lane = tid & 63;
    __shared__ int sB[2];
    if (wave < 2) {
        int r = wave_lower_bound(dst, NE0, n + wave, lane);
        if (lane == 0) sB[wave] = r;
    }
    __syncthreads();
    const int e0 = sB[0];
    const int e1 = sB[1];
    const int len = e1 - e0;
    const int q0 = e0 + (len * wave) / 4;
    const int q1 = e0 + (len * (wave + 1)) / 4;
    __shared__ int wcnt[4][NB];
    __shared__ int wbase[4][NB];

    // phase 1: per-wave bucket counts via ballot (no atomics)
    int c0 = 0, c1 = 0, c2 = 0, c3 = 0;
    for (int base = q0; base < q1; base += 64) {
        int e = base + lane;
        int b = -1;
        if (e < q1) b = src[e] / SRC_PER_B;
        c0 += __popcll(__ballot(b == 0));
        c1 += __popcll(__ballot(b == 1));
        c2 += __popcll(__ballot(b == 2));
        c3 += __popcll(__ballot(b == 3));
    }
    if (lane == 0) { wcnt[wave][0] = c0; wcnt[wave][1] = c1; wcnt[wave][2] = c2; wcnt[wave][3] = c3; }
    __syncthreads();
    if (tid == 0) {
        int acc = e0;
        #pragma unroll
        for (int b = 0; b < NB; ++b) {
            bstart[n * (NB + 1) + b] = acc;
            #pragma unroll
            for (int w = 0; w < 4; ++w) { wbase[w][b] = acc; acc += wcnt[w][b]; }
        }
        bstart[n * (NB + 1) + NB] = acc;   // == e1
    }
    __syncthreads();

    // phase 2: stable scatter (deterministic order), register cursors;
    // per-bucket writes from a wave are consecutive -> coalesced runs.
    int u0 = wbase[wave][0], u1 = wbase[wave][1], u2 = wbase[wave][2], u3 = wbase[wave][3];
    for (int base = q0; base < q1; base += 64) {
        int e = base + lane;
        int s = 0, b = -1;
        if (e < q1) { s = src[e]; b = s / SRC_PER_B; }
        unsigned long long m0 = __ballot(b == 0);
        unsigned long long m1 = __ballot(b == 1);
        unsigned long long m2 = __ballot(b == 2);
        unsigned long long m3 = __ballot(b == 3);
        unsigned long long lt = (1ull << lane) - 1ull;
        if (b == 0)      esrc[u0 + __popcll(m0 & lt)] = s;
        else if (b == 1) esrc[u1 + __popcll(m1 & lt)] = s;
        else if (b == 2) esrc[u2 + __popcll(m2 & lt)] = s;
        else if (b == 3) esrc[u3 + __popcll(m3 & lt)] = s;
        u0 += __popcll(m0); u1 += __popcll(m1); u2 += __popcll(m2); u3 += __popcll(m3);
    }
}

// Layer-0 gather over bucket-partitioned edges, 64 B rows (1 L2 line/edge).
// Block (n, b): contiguous bucket range; table slice b (3.2 MB) L2-resident
// on XCDs {b, b+4} (blockIdx & 3 == b). 128 thr, 4-deep chains, LDS tree
// reduce, fp16 partial output (summed inline by gather1). ~10-12 us (round-19
// attribution probe) -- at its L2-residency floor.
__global__ __launch_bounds__(128) void k_gather0s(const h8* __restrict__ table,
                                                  const int* __restrict__ esrc,
                                                  const int* __restrict__ bstart,
                                                  _Float16* __restrict__ p0p) {
    const int b = blockIdx.x & (NB - 1);
    const int n = blockIdx.x >> 2;
    const int q0 = bstart[n * (NB + 1) + b];
    const int q1 = bstart[n * (NB + 1) + b + 1];
    const int tid = threadIdx.x;
    const int b4 = tid & 3;      // which 16B chunk of the 64B row
    const int g  = tid >> 2;     // 32 edge groups
    float acc[8] = {0.f, 0.f, 0.f, 0.f, 0.f, 0.f, 0.f, 0.f};
    int e = q0 + g;
    for (; e + 96 < q1; e += 128) {
        int s0 = esrc[e];
        int s1 = esrc[e + 32];
        int s2 = esrc[e + 64];
        int s3 = esrc[e + 96];
        h8 v0 = table[s0 * 4 + b4];
        h8 v1 = table[s1 * 4 + b4];
        h8 v2 = table[s2 * 4 + b4];
        h8 v3 = table[s3 * 4 + b4];
        #pragma unroll
        for (int i = 0; i < 8; ++i)
            acc[i] += (float)v0[i] + (float)v1[i] + (float)v2[i] + (float)v3[i];
    }
    for (; e < q1; e += 32) {
        int s = esrc[e];
        h8 v = table[s * 4 + b4];
        #pragma unroll
        for (int i = 0; i < 8; ++i) acc[i] += (float)v[i];
    }
    __shared__ float red[32][33];
    #pragma unroll
    for (int i = 0; i < 8; ++i) red[g][b4 * 8 + i] = acc[i];
    __syncthreads();
    #pragma unroll
    for (int s = 16; s >= 1; s >>= 1) {
        if (g < s) {
            #pragma unroll
            for (int i = 0; i < 8; ++i)
                red[g][b4 * 8 + i] += red[g + s][b4 * 8 + i];
        }
        __syncthreads();
    }
    if (tid < 32) p0p[(b * N1 + n) * 32 + tid] = (_Float16)red[0][tid];
}

// Dispatch 3: blocks [0,N2) = layer-1 gather (sums the NB fp16 partial
// planes inline); blocks [N2, N2+NCLS) = weight-chain + Vfc precompute.
__global__ __launch_bounds__(256) void k_gather1w(
    const h8* __restrict__ p0p, const int* __restrict__ src,
    const int* __restrict__ dst, _Float16* __restrict__ out_h,
    float* __restrict__ cnt_out,
    const float* __restrict__ V0, const float* __restrict__ g0, const float* __restrict__ b0,
    const float* __restrict__ V1, const float* __restrict__ g1, const float* __restrict__ b1,
    const float* __restrict__ V2, const float* __restrict__ g2, const float* __restrict__ b2,
    const float* __restrict__ Vfc, const float* __restrict__ gfc,
    float* __restrict__ M_, float* __restrict__ Q2_, float* __restrict__ R2_,
    float* __restrict__ B4_) {
    const int tid = threadIdx.x;
    if (blockIdx.x < N2) {
        // ---- gather1 role ----
        const int n = blockIdx.x;
        const int e0 = lower_bound_i(dst, NE1, n);
        const int e1 = lower_bound_i(dst, NE1, n + 1);
        const int b4 = tid & 3;
        const int g  = tid >> 2;
        float acc[8] = {0.f, 0.f, 0.f, 0.f, 0.f, 0.f, 0.f, 0.f};
        for (int e = e0 + g; e < e1; e += 64) {
            int s = src[e];
            h8 v0 = p0p[0 * N1 * 4 + s * 4 + b4];
            h8 v1 = p0p[1 * N1 * 4 + s * 4 + b4];
            h8 v2 = p0p[2 * N1 * 4 + s * 4 + b4];
            h8 v3 = p0p[3 * N1 * 4 + s * 4 + b4];
            #pragma unroll
            for (int i = 0; i < 8; ++i)
                acc[i] += ((float)v0[i] + (float)v1[i]) + ((float)v2[i] + (float)v3[i]);
        }
        __shared__ float red[64][33];
        #pragma unroll
        for (int i = 0; i < 8; ++i) red[g][b4 * 8 + i] = acc[i];
        __syncthreads();
        #pragma unroll
        for (int s = 32; s >= 1; s >>= 1) {
            if (g < s) {
                #pragma unroll
                for (int i = 0; i < 8; ++i)
                    red[g][b4 * 8 + i] += red[g + s][b4 * 8 + i];
            }
            __syncthreads();
        }
        if (tid < 32) out_h[n * 32 + tid] = (_Float16)red[0][tid];
        else if (tid == 32) cnt_out[n] = (float)(e1 - e0);
        return;
    }
    // ---- weights role: class k ----
    const int k = blockIdx.x - N2;
    __shared__ float w0[32], u[64], v[64], p[128], q[128], r[128];
    __shared__ float redA[8][32], redB[8][32], redC[8][32], redD[8][32];
    __shared__ float nnred[4];
    __shared__ float scale_s;

    if (tid < 32) {
        float val = V0[tid];
        w0[tid] = g0[tid] * val / fabsf(val);
    }
    __syncthreads();
    if (tid < 64) {
        float nn = 0.f;
        #pragma unroll
        for (int c = 0; c < 32; ++c) { float t = V1[tid * 32 + c]; nn += t * t; }
        float inv = g1[tid] * rsqrtf(nn);
        float su = 0.f, sv = 0.f;
        #pragma unroll
        for (int c = 0; c < 32; ++c) {
            float w = V1[tid * 32 + c] * inv;
            su += w * w0[c]; sv += w * b0[c];
        }
        u[tid] = su; v[tid] = sv;
    }
    __syncthreads();
    if (tid < 128) {
        float nn = 0.f;
        #pragma unroll
        for (int c = 0; c < 64; ++c) { float t = V2[tid * 64 + c]; nn += t * t; }
        float inv = g2[tid] * rsqrtf(nn);
        float sp = 0.f, sq = 0.f, sr = 0.f;
        #pragma unroll
        for (int c = 0; c < 64; ++c) {
            float w = V2[tid * 64 + c] * inv;
            sp += w * u[c]; sq += w * v[c]; sr += w * b1[c];
        }
        p[tid] = sp; q[tid] = sq; r[tid] = sr;
    }
    __syncthreads();

    const int n3 = tid & 31, og = tid >> 5;
    float nn = 0.f, mk = 0.f, mq = 0.f, mr = 0.f, mb = 0.f;
    #pragma unroll
    for (int i = 0; i < 16; ++i) {
        int o = og + 8 * i;
        float w = Vfc[k * 4096 + tid + 256 * i];
        nn += w * w;
        mk += w * p[o]; mq += w * q[o]; mr += w * r[o]; mb += w * b2[o];
    }
    #pragma unroll
    for (int off = 32; off; off >>= 1) nn += __shfl_xor(nn, off);
    if ((tid & 63) == 0) nnred[tid >> 6] = nn;
    redA[og][n3] = mk; redB[og][n3] = mq; redC[og][n3] = mr; redD[og][n3] = mb;
    __syncthreads();
    if (tid == 0) {
        float s = nnred[0] + nnred[1] + nnred[2] + nnred[3];
        scale_s = gfc[k] * rsqrtf(s);
    }
    __syncthreads();
    if (tid < 32) {
        float smk = 0.f, smq = 0.f, smr = 0.f, smb = 0.f;
        #pragma unroll
        for (int i = 0; i < 8; ++i) {
            smk += redA[i][tid]; smq += redB[i][tid];
            smr += redC[i][tid]; smb += redD[i][tid];
        }
        float scale = scale_s;
        M_[k * 32 + tid]  = scale * smk;
        Q2_[k * 32 + tid] = scale * smq;
        R2_[k * 32 + tid] = scale * smr;
        float bs = scale * smb;
        #pragma unroll
        for (int off = 16; off; off >>= 1) bs += __shfl_xor(bs, off);
        if (tid == 0) B4_[k] = bs;
    }
}

// Layer-2 gather (32 segments, 16 KB table): writes fp32 S2, T2, cnt2.
__global__ __launch_bounds__(256) void k_gather2(const h8* __restrict__ table,
                                                 const int* __restrict__ src,
                                                 const int* __restrict__ dst,
                                                 const float* __restrict__ cnt_in,
                                                 float* __restrict__ out_f,
                                                 float* __restrict__ cnt_out,
                                                 float* __restrict__ t_out) {
    const int n = blockIdx.x;
    const int e0 = lower_bound_i(dst, NE2, n);
    const int e1 = lower_bound_i(dst, NE2, n + 1);
    const int tid = threadIdx.x;
    const int b4 = tid & 3;
    const int g  = tid >> 2;
    float acc[8] = {0.f, 0.f, 0.f, 0.f, 0.f, 0.f, 0.f, 0.f};
    float tacc = 0.f;
    for (int e = e0 + g; e < e1; e += 64) {
        int s = src[e];
        h8 v = table[s * 4 + b4];
        #pragma unroll
        for (int i = 0; i < 8; ++i) acc[i] += (float)v[i];
        if (b4 == 0) tacc += cnt_in[s];
    }
    __shared__ float red[64][33];
    __shared__ float tred[64];
    #pragma unroll
    for (int i = 0; i < 8; ++i) red[g][b4 * 8 + i] = acc[i];
    if (b4 == 0) tred[g] = tacc;
    __syncthreads();
    #pragma unroll
    for (int s = 32; s >= 1; s >>= 1) {
        if (g < s) {
            #pragma unroll
            for (int i = 0; i < 8; ++i)
                red[g][b4 * 8 + i] += red[g + s][b4 * 8 + i];
            if (b4 == 0) tred[g] += tred[g + s];
        }
        __syncthreads();
    }
    if (tid < 32) out_f[n * 32 + tid] = red[0][tid];
    else if (tid == 32) cnt_out[n] = (float)(e1 - e0);
    else if (tid == 33) t_out[n] = tred[0];
}

// Tiny final combine: block per class.
__global__ __launch_bounds__(64) void k_final(const float* __restrict__ M_,
                                              const float* __restrict__ Q2_,
                                              const float* __restrict__ R2_,
                                              const float* __restrict__ B4_,
                                              const float* __restrict__ bfc,
                                              const float* __restrict__ S2,
                                              const float* __restrict__ T2,
                                              const float* __restrict__ cnt2,
                                              float* __restrict__ out) {
    const int k = blockIdx.x;
    const int tid = threadIdx.x;
    __shared__ float Kc_s;
    float kc = 0.f;
    if (tid < 32)
        kc = Q2_[k * 32 + tid] * T2[tid] + R2_[k * 32 + tid] * cnt2[tid];
    #pragma unroll
    for (int off = 16; off; off >>= 1) kc += __shfl_xor(kc, off);
    if (tid == 0) Kc_s = kc + B4_[k] + bfc[k];
    __syncthreads();
    if (tid < 32) {
        int b = tid;
        float s = 0.f;
        #pragma unroll
        for (int n = 0; n < 32; ++n) s += M_[k * 32 + n] * S2[n * 32 + b];
        out[b * NCLS + k] = s + Kc_s;
    }
}

extern "C" void kernel_launch(void* const* d_in, const int* in_sizes, int n_in,
                              void* d_out, int out_size, void* d_ws, size_t ws_size,
                              hipStream_t stream) {
    const float* x   = (const float*)d_in[0];
    const int* src0  = (const int*)d_in[1];
    const int* dst0  = (const int*)d_in[2];
    const int* src1  = (const int*)d_in[3];
    const int* dst1  = (const int*)d_in[4];
    const int* src2  = (const int*)d_in[5];
    const int* dst2  = (const int*)d_in[6];
    const float* V0  = (const float*)d_in[7];
    const float* g0  = (const float*)d_in[8];
    const float* b0  = (const float*)d_in[9];
    const float* V1  = (const float*)d_in[10];
    const float* g1  = (const float*)d_in[11];
    const float* b1  = (const float*)d_in[12];
    const float* V2  = (const float*)d_in[13];
    const float* g2  = (const float*)d_in[14];
    const float* b2  = (const float*)d_in[15];
    const float* Vfc = (const float*)d_in[16];
    const float* gfc = (const float*)d_in[17];
    const float* bfc = (const float*)d_in[18];

    char* ws = (char*)d_ws;
    _Float16* xt   = (_Float16*)(ws);                // 12,800,000 B
    int* esrc      = (int*)(ws + 12800000);          // 8,192,000 B
    int* bstart    = (int*)(ws + 20992000);          // 20,480 B
    _Float16* P0p  = (_Float16*)(ws + 21012480);     // 262,144 B
    _Float16* S1h  = (_Float16*)(ws + 21274624);     // 16,384 B
    float* cnt1    = (float*)(ws + 21291008);        // 1,024 B
    float* S2      = (float*)(ws + 21292032);        // 4,096 B
    float* T2      = (float*)(ws + 21296128);        // 128 B
    float* cnt2    = (float*)(ws + 21296256);        // 128 B
    float* M_      = (float*)(ws + 21296384);        // 1,280 B
    float* Q2_     = (float*)(ws + 21297664);        // 1,280 B
    float* R2_     = (float*)(ws + 21298944);        // 1,280 B
    float* B4_     = (float*)(ws + 21300224);        // 40 B

    k_pre<<<PREBLOCKS, 256, 0, stream>>>(x, (h2*)xt, src0, dst0, esrc, bstart);
    k_gather0s<<<N1 * NB, 128, 0, stream>>>((const h8*)xt, esrc, bstart,
                                            (_Float16*)P0p);
    k_gather1w<<<N2 + NCLS, 256, 0, stream>>>((const h8*)P0p, src1, dst1,
                                              S1h, cnt1,
                                              V0, g0, b0, V1, g1, b1,
                                              V2, g2, b2, Vfc, gfc,
                                              M_, Q2_, R2_, B4_);
    k_gather2<<<N3, 256, 0, stream>>>((const h8*)S1h, src2, dst2, cnt1,
                                      S2, cnt2, T2);
    k_final<<<NCLS, 64, 0, stream>>>(M_, Q2_, R2_, B4_, bfc, S2, T2, cnt2,
                                     (float*)d_out);
}